// Round 15
// baseline (178.869 us; speedup 1.0000x reference)
//
#include <hip/hip_runtime.h>
#include <math.h>
#include <string.h>

#define TPB    512        // threads per block (8 waves)
#define KPT    32         // keys per thread; n = TPB*KPT = 16384
#define CAP    2048       // LDS candidate capacity
#define CAPREG 512        // tier-A cap: 8 regs/lane * 64 lanes
#define NWAVE  (TPB/64)

typedef float f32x4 __attribute__((ext_vector_type(4)));   // native vec for NT store

// ---------------- boost precompute: boost = f32(exp(f64(1.5f*(0.02f - dc)))) ----
__global__ void boost_kernel(const float* __restrict__ dc, float* __restrict__ boost, int n) {
    int i = blockIdx.x * blockDim.x + threadIdx.x;
    if (i < n) {
        float a = 1.5f * (0.02f - dc[i]);   // exact f32 arithmetic, same as reference
        boost[i] = (float)exp((double)a);   // correctly-rounded f32 exp via f64
    }
}

// monotone float -> uint32 key (only used in the ~never-taken tier-C fallback)
__device__ __forceinline__ unsigned fkey(float f) {
    unsigned u = __float_as_uint(f);
    return (u & 0x80000000u) ? ~u : (u | 0x80000000u);
}

// wave-wide sums of per-lane counts via bit-plane ballots; uniform result.
__device__ __forceinline__ int wave_sum6(int c) {
    int t;
    t  = (int)__popcll(__ballot(c & 1));
    t += (int)__popcll(__ballot(c & 2))  << 1;
    t += (int)__popcll(__ballot(c & 4))  << 2;
    t += (int)__popcll(__ballot(c & 8))  << 3;
    t += (int)__popcll(__ballot(c & 16)) << 4;
    t += (int)__popcll(__ballot(c & 32)) << 5;
    return t;
}
__device__ __forceinline__ int wave_sum4(int c) {   // counts <= 8 per lane
    int t;
    t  = (int)__popcll(__ballot(c & 1));
    t += (int)__popcll(__ballot(c & 2)) << 1;
    t += (int)__popcll(__ballot(c & 4)) << 2;
    t += (int)__popcll(__ballot(c & 8)) << 3;
    return t;
}

// ==== one-pass: float-domain scan-compact -> reg-cached 1-wave bisect -> NT write ====
template<bool USE_B>
__global__ __launch_bounds__(TPB, 8)
void kwta_scan(const float* __restrict__ x,
               const float* __restrict__ boost,
               const float* __restrict__ dc,
               float* __restrict__ out,
               int n, int k, float PIVF) {
    const int tid  = threadIdx.x;
    const int lane = tid & 63;
    const int wave = tid >> 6;
    const int row  = blockIdx.x;

    __shared__ unsigned s_key[CAP];      // candidate float bits (all positive)
    __shared__ int s_wtot[NWAVE];
    __shared__ int s_cnt[4];
    __shared__ unsigned s_P;

    // ---- load row, build 32 boosted values/thread (float domain, no fkey) ----
    const float4* x4 = (const float4*)(x + (size_t)row * n);
    const float4* b4 = (const float4*)boost;
    const float4* d4 = (const float4*)dc;
    float xb[KPT];
    #pragma unroll
    for (int i = 0; i < KPT/4; ++i) {
        float4 xv = x4[tid + i * TPB];
        if (USE_B) {
            float4 bv = b4[tid + i * TPB];
            xb[4*i+0] = xv.x * bv.x;
            xb[4*i+1] = xv.y * bv.y;
            xb[4*i+2] = xv.z * bv.z;
            xb[4*i+3] = xv.w * bv.w;
        } else {
            float4 dv = d4[tid + i * TPB];
            xb[4*i+0] = xv.x * (float)exp((double)(1.5f * (0.02f - dv.x)));
            xb[4*i+1] = xv.y * (float)exp((double)(1.5f * (0.02f - dv.y)));
            xb[4*i+2] = xv.z * (float)exp((double)(1.5f * (0.02f - dv.z)));
            xb[4*i+3] = xv.w * (float)exp((double)(1.5f * (0.02f - dv.w)));
        }
    }

    // ---- per-thread candidate count ----
    int c = 0;
    #pragma unroll
    for (int j = 0; j < KPT; ++j) c += (xb[j] >= PIVF) ? 1 : 0;

    // ---- wave exclusive scan + total via bit-plane ballots ----
    const unsigned long long lt = (1ull << lane) - 1ull;
    int pre = 0, wt = 0;
    #pragma unroll
    for (int b = 0; b < 6; ++b) {
        unsigned long long m = __ballot((c >> b) & 1);
        pre += (int)__popcll(m & lt) << b;
        wt  += (int)__popcll(m) << b;
    }
    if (tid < 4) s_cnt[tid] = 0;
    if (lane == 0) s_wtot[wave] = wt;
    __syncthreads();                     // (1) wave totals visible

    int base = 0, nc = 0;
    #pragma unroll
    for (int w = 0; w < NWAVE; ++w) {
        const int t = s_wtot[w];
        base += (w < wave) ? t : 0;
        nc   += t;
    }
    int off = base + pre;

    #pragma unroll
    for (int j = 0; j < KPT; ++j) {
        if (xb[j] >= PIVF) {
            if (off < CAP) s_key[off] = __float_as_uint(xb[j]);  // positive -> uint order
            ++off;
        }
    }
    __syncthreads();                     // (2) candidate list ready

    float Pf;
    if (nc >= k && nc <= CAPREG) {
        // ---- tier A: ONE wave, candidates cached in 8 regs, pure-register bisect ----
        if (wave == (row & (NWAVE - 1))) {
            unsigned cand[8];
            #pragma unroll
            for (int j = 0; j < 8; ++j) {
                const int idx = lane + (j << 6);
                cand[j] = (idx < nc) ? s_key[idx] : 0u;   // 0 never >= probe
            }
            unsigned Q = 0;
            for (int b = 30; b >= 0; b -= 2) {
                const unsigned CA = Q | (1u << (b + 1));
                const unsigned CB = Q | (1u << b);
                const unsigned CC = CA | (1u << b);
                int ca = 0, cb = 0, cc = 0;
                #pragma unroll
                for (int j = 0; j < 8; ++j) {
                    ca += (cand[j] >= CA) ? 1 : 0;
                    cb += (cand[j] >= CB) ? 1 : 0;
                    cc += (cand[j] >= CC) ? 1 : 0;
                }
                const int A = wave_sum4(ca);
                const int B = wave_sum4(cb);
                const int C = wave_sum4(cc);
                if (A >= k)      Q = (C >= k) ? CC : CA;
                else if (B >= k) Q = CB;
            }
            if (lane == 0) s_P = Q;
        }
        __syncthreads();                 // (3) P published (no stores in flight yet)
        Pf = __uint_as_float(s_P);
    } else if (nc >= k && nc <= CAP) {
        // ---- tier B: single-wave LDS-read bisect (nc in (512, 2048]) ----
        if (wave == (row & (NWAVE - 1))) {
            const int mrd = (nc + 63) >> 6;
            unsigned Q = 0;
            for (int b = 30; b >= 0; b -= 2) {
                const unsigned CA = Q | (1u << (b + 1));
                const unsigned CB = Q | (1u << b);
                const unsigned CC = CA | (1u << b);
                int ca = 0, cb = 0, cc = 0;
                for (int j = 0; j < mrd; ++j) {
                    const int idx = lane + (j << 6);
                    const unsigned v = (idx < nc) ? s_key[idx] : 0u;
                    ca += (v >= CA) ? 1 : 0;
                    cb += (v >= CB) ? 1 : 0;
                    cc += (v >= CC) ? 1 : 0;
                }
                const int A = wave_sum6(ca);
                const int B = wave_sum6(cb);
                const int C = wave_sum6(cc);
                if (A >= k)      Q = (C >= k) ? CC : CA;
                else if (B >= k) Q = CB;
            }
            if (lane == 0) s_P = Q;
        }
        __syncthreads();
        Pf = __uint_as_float(s_P);
    } else {
        // ---- tier C (~never): exact block-wide bisect in fkey space, any data ----
        int it = 0;
        unsigned P = 0;
        for (int b = 31; b >= 0; --b) {
            const unsigned C = P | (1u << b);
            int cc = 0;
            #pragma unroll
            for (int j = 0; j < KPT; ++j) cc += (fkey(xb[j]) >= C) ? 1 : 0;
            int t = wave_sum6(cc);
            const int s = it & 3;
            if (lane == 0) atomicAdd(&s_cnt[s], t);
            __syncthreads();
            const int total = s_cnt[s];
            if (tid == 0) s_cnt[(s + 2) & 3] = 0;
            ++it;
            if (total >= k) P = C;
        }
        Pf = (P & 0x80000000u) ? __uint_as_float(P ^ 0x80000000u)
                               : __uint_as_float(~P);
    }

    // ---- dense contiguous NT write; IEEE float >= matches reference exactly ----
    f32x4* o4 = (f32x4*)(out + (size_t)row * n);
    #pragma unroll
    for (int i = 0; i < KPT/4; ++i) {
        f32x4 o;
        o.x = (xb[4*i+0] >= Pf) ? 1.0f : 0.0f;
        o.y = (xb[4*i+1] >= Pf) ? 1.0f : 0.0f;
        o.z = (xb[4*i+2] >= Pf) ? 1.0f : 0.0f;
        o.w = (xb[4*i+3] >= Pf) ? 1.0f : 0.0f;
        __builtin_nontemporal_store(o, &o4[tid + i * TPB]);
    }
}

extern "C" void kernel_launch(void* const* d_in, const int* in_sizes, int n_in,
                              void* d_out, int out_size, void* d_ws, size_t ws_size,
                              hipStream_t stream) {
    const float* x  = (const float*)d_in[0];
    const float* dc = (const float*)d_in[1];
    float* out = (float*)d_out;

    int n    = in_sizes[1];             // 16384
    int rows = in_sizes[0] / n;         // 4096
    int k    = (int)llround((double)n * 0.02);
    if (k < 1) k = 1;

    // fixed conservative pivot: xb >= 1.15 -> ~500+-22 candidates/row on this data
    // (tier-A reg cap 512, tier-B LDS cap 2048); exact tier-C covers any data.
    const float PIVF = 1.15f;

    if (ws_size >= (size_t)n * sizeof(float)) {
        float* boost = (float*)d_ws;
        boost_kernel<<<(n + 255) / 256, 256, 0, stream>>>(dc, boost, n);
        kwta_scan<true><<<rows, TPB, 0, stream>>>(x, boost, dc, out, n, k, PIVF);
    } else {
        kwta_scan<false><<<rows, TPB, 0, stream>>>(x, nullptr, dc, out, n, k, PIVF);
    }
}

// Round 16
// 93.695 us; speedup vs baseline: 1.9091x; 1.9091x over previous
//
#include <hip/hip_runtime.h>
#include <math.h>
#include <string.h>

#define TPB    512        // threads per block (8 waves)
#define KPT    32         // keys per thread; n = TPB*KPT = 16384
#define CAP    2048       // candidate list capacity (8 KiB LDS)
#define CAPREG 512        // tier-A cap: 8 regs/lane * 64 lanes
#define NWAVE  (TPB/64)

typedef float f32x4 __attribute__((ext_vector_type(4)));   // native vec for NT store

// ---------------- boost precompute: boost = f32(exp(f64(1.5f*(0.02f - dc)))) ----
__global__ void boost_kernel(const float* __restrict__ dc, float* __restrict__ boost, int n) {
    int i = blockIdx.x * blockDim.x + threadIdx.x;
    if (i < n) {
        float a = 1.5f * (0.02f - dc[i]);   // exact f32 arithmetic, same as reference
        boost[i] = (float)exp((double)a);   // correctly-rounded f32 exp via f64
    }
}

// monotone float -> uint32 key (no NaNs in input)
__device__ __forceinline__ unsigned fkey(float f) {
    unsigned u = __float_as_uint(f);
    return (u & 0x80000000u) ? ~u : (u | 0x80000000u);
}

// wave-wide sum of per-lane count c (0..63) via bit-plane ballots; uniform result.
__device__ __forceinline__ int wave_sum6(int c) {
    int t;
    t  = (int)__popcll(__ballot(c & 1));
    t += (int)__popcll(__ballot(c & 2))  << 1;
    t += (int)__popcll(__ballot(c & 4))  << 2;
    t += (int)__popcll(__ballot(c & 8))  << 3;
    t += (int)__popcll(__ballot(c & 16)) << 4;
    t += (int)__popcll(__ballot(c & 32)) << 5;
    return t;
}
__device__ __forceinline__ int wave_sum4(int c) {   // counts <= 8 per lane
    int t;
    t  = (int)__popcll(__ballot(c & 1));
    t += (int)__popcll(__ballot(c & 2)) << 1;
    t += (int)__popcll(__ballot(c & 4)) << 2;
    t += (int)__popcll(__ballot(c & 8)) << 3;
    return t;
}

// ======== one-pass: reg-resident keys -> scan-compact -> 1-wave bisect -> write ====
template<bool USE_B>
__global__ __launch_bounds__(TPB, 8)
void kwta_scan(const float* __restrict__ x,
               const float* __restrict__ boost,
               const float* __restrict__ dc,
               float* __restrict__ out,
               int n, int k, unsigned PIV) {
    const int tid  = threadIdx.x;
    const int lane = tid & 63;
    const int wave = tid >> 6;
    const int row  = blockIdx.x;

    __shared__ unsigned s_key[CAP];
    __shared__ int s_wtot[NWAVE];
    __shared__ int s_cnt[4];
    __shared__ unsigned s_P;

    // ---- load row, build 32 keys/thread in registers ----
    const float4* x4 = (const float4*)(x + (size_t)row * n);
    const float4* b4 = (const float4*)boost;
    const float4* d4 = (const float4*)dc;
    unsigned key[KPT];
    #pragma unroll
    for (int i = 0; i < KPT/4; ++i) {
        float4 xv = x4[tid + i * TPB];
        if (USE_B) {
            float4 bv = b4[tid + i * TPB];
            key[4*i+0] = fkey(xv.x * bv.x);
            key[4*i+1] = fkey(xv.y * bv.y);
            key[4*i+2] = fkey(xv.z * bv.z);
            key[4*i+3] = fkey(xv.w * bv.w);
        } else {
            float4 dv = d4[tid + i * TPB];
            key[4*i+0] = fkey(xv.x * (float)exp((double)(1.5f * (0.02f - dv.x))));
            key[4*i+1] = fkey(xv.y * (float)exp((double)(1.5f * (0.02f - dv.y))));
            key[4*i+2] = fkey(xv.z * (float)exp((double)(1.5f * (0.02f - dv.z))));
            key[4*i+3] = fkey(xv.w * (float)exp((double)(1.5f * (0.02f - dv.w))));
        }
    }

    // ---- per-thread candidate count ----
    int c = 0;
    #pragma unroll
    for (int j = 0; j < KPT; ++j) c += (key[j] >= PIV) ? 1 : 0;

    // ---- wave-level exclusive scan + total via bit-plane ballots (no chain) ----
    const unsigned long long lt = (1ull << lane) - 1ull;
    int pre = 0, wt = 0;
    #pragma unroll
    for (int b = 0; b < 6; ++b) {
        unsigned long long m = __ballot((c >> b) & 1);
        pre += (int)__popcll(m & lt) << b;
        wt  += (int)__popcll(m) << b;
    }
    if (tid < 4) s_cnt[tid] = 0;         // reset for potential fallback
    if (lane == 0) s_wtot[wave] = wt;
    __syncthreads();                     // (1) wave totals visible

    int base = 0, nc = 0;
    #pragma unroll
    for (int w = 0; w < NWAVE; ++w) {
        const int t = s_wtot[w];
        base += (w < wave) ? t : 0;
        nc   += t;
    }
    int off = base + pre;

    // ---- append candidates at scanned offsets (atomic-free) ----
    #pragma unroll
    for (int j = 0; j < KPT; ++j) {
        if (key[j] >= PIV) {
            if (off < CAP) s_key[off] = key[j];
            ++off;
        }
    }
    __syncthreads();                     // (2) candidate list ready

    unsigned P;
    if (nc >= k && nc <= CAPREG) {
        // ---- tier A: one wave, candidates cached in 8 regs, pure-register rounds ----
        if (wave == (row & (NWAVE - 1))) {
            unsigned cand[8];
            #pragma unroll
            for (int j = 0; j < 8; ++j) {
                const int idx = lane + (j << 6);
                cand[j] = (idx < nc) ? s_key[idx] : 0u;   // 0 never >= probe
            }
            unsigned Q = 0;
            for (int b = 30; b >= 0; b -= 2) {
                const unsigned CA = Q | (1u << (b + 1));
                const unsigned CB = Q | (1u << b);
                const unsigned CC = CA | (1u << b);
                int ca = 0, cb = 0, cc = 0;
                #pragma unroll
                for (int j = 0; j < 8; ++j) {
                    ca += (cand[j] >= CA) ? 1 : 0;
                    cb += (cand[j] >= CB) ? 1 : 0;
                    cc += (cand[j] >= CC) ? 1 : 0;
                }
                const int A = wave_sum4(ca);
                const int B = wave_sum4(cb);
                const int C = wave_sum4(cc);
                if (A >= k)      Q = (C >= k) ? CC : CA;
                else if (B >= k) Q = CB;
            }
            if (lane == 0) s_P = Q;
        }
        __syncthreads();                 // (3) P published
        P = s_P;
    } else if (nc >= k && nc <= CAP) {
        // ---- tier B: single-wave LDS-read bisect (nc in (512, 2048]) ----
        if (wave == (row & (NWAVE - 1))) {
            const int mrd = (nc + 63) >> 6;
            unsigned Q = 0;
            for (int b = 30; b >= 0; b -= 2) {
                const unsigned CA = Q | (1u << (b + 1));
                const unsigned CB = Q | (1u << b);
                const unsigned CC = CA | (1u << b);
                int ca = 0, cb = 0, cc = 0;
                for (int j = 0; j < mrd; ++j) {
                    const int idx = lane + (j << 6);
                    const unsigned v = (idx < nc) ? s_key[idx] : 0u;  // 0 never >= probe
                    ca += (v >= CA) ? 1 : 0;
                    cb += (v >= CB) ? 1 : 0;
                    cc += (v >= CC) ? 1 : 0;
                }
                const int A = wave_sum6(ca);
                const int B = wave_sum6(cb);
                const int C = wave_sum6(cc);
                if (A >= k)      Q = (C >= k) ? CC : CA;
                else if (B >= k) Q = CB;
            }
            if (lane == 0) s_P = Q;
        }
        __syncthreads();                 // (3) P published
        P = s_P;
    } else {
        // ---- tier C (~never): block-wide 32-round bisect over register keys ----
        int it = 0;
        P = 0;
        for (int b = 31; b >= 0; --b) {
            const unsigned C = P | (1u << b);
            int cc = 0;
            #pragma unroll
            for (int j = 0; j < KPT; ++j) cc += (key[j] >= C) ? 1 : 0;
            int t = wave_sum6(cc);
            const int s = it & 3;
            if (lane == 0) atomicAdd(&s_cnt[s], t);
            __syncthreads();
            const int total = s_cnt[s];
            if (tid == 0) s_cnt[(s + 2) & 3] = 0;
            ++it;
            if (total >= k) P = C;
        }
    }

    // ---- dense write straight from registers; nontemporal float4 stream ----
    f32x4* o4 = (f32x4*)(out + (size_t)row * n);
    #pragma unroll
    for (int i = 0; i < KPT/4; ++i) {
        f32x4 o;
        o.x = (key[4*i+0] >= P) ? 1.0f : 0.0f;
        o.y = (key[4*i+1] >= P) ? 1.0f : 0.0f;
        o.z = (key[4*i+2] >= P) ? 1.0f : 0.0f;
        o.w = (key[4*i+3] >= P) ? 1.0f : 0.0f;
        __builtin_nontemporal_store(o, &o4[tid + i * TPB]);
    }
}

extern "C" void kernel_launch(void* const* d_in, const int* in_sizes, int n_in,
                              void* d_out, int out_size, void* d_ws, size_t ws_size,
                              hipStream_t stream) {
    const float* x  = (const float*)d_in[0];
    const float* dc = (const float*)d_in[1];
    float* out = (float*)d_out;

    int n    = in_sizes[1];             // 16384
    int rows = in_sizes[0] / n;         // 4096
    int k    = (int)llround((double)n * 0.02);
    if (k < 1) k = 1;

    // fixed conservative pivot: xb >= 1.15 -> ~500+-22 candidates/row on this data
    // (tier-A reg cap 512, tier-B LDS cap 2048); exact tier-C covers any data.
    float pivf = 1.15f;
    unsigned pu;
    memcpy(&pu, &pivf, sizeof(pu));
    unsigned PIV = (pu & 0x80000000u) ? ~pu : (pu | 0x80000000u);

    if (ws_size >= (size_t)n * sizeof(float)) {
        float* boost = (float*)d_ws;
        boost_kernel<<<(n + 255) / 256, 256, 0, stream>>>(dc, boost, n);
        kwta_scan<true><<<rows, TPB, 0, stream>>>(x, boost, dc, out, n, k, PIV);
    } else {
        kwta_scan<false><<<rows, TPB, 0, stream>>>(x, nullptr, dc, out, n, k, PIV);
    }
}